// Round 9
// baseline (429.046 us; speedup 1.0000x reference)
//
#include <hip/hip_runtime.h>

// Problem constants (fixed by reference)
constexpr int NN   = 20000;          // nodes
constexpr int NE   = 320000;         // edges (before self-loops)
constexpr int NTOT = NE + NN;        // edges incl self-loops
constexpr int FIN  = 128;
constexpr int HID  = 256;
constexpr int NG   = 128;            // graphs
constexpr int NCLS = 10;

typedef __bf16 bf16x8 __attribute__((ext_vector_type(8)));
typedef float  f32x4  __attribute__((ext_vector_type(4)));

__device__ __forceinline__ unsigned short f2b(float f) {
  unsigned u = __float_as_uint(f);
  unsigned r = (u + 0x7fffu + ((u >> 16) & 1u)) >> 16;
  return (unsigned short)r;
}
__device__ __forceinline__ float b2f(unsigned short h) {
  return __uint_as_float((unsigned)h << 16);
}
// ordered-uint encoding for float atomicMax
__device__ __forceinline__ unsigned fenc(float f) {
  unsigned b = __float_as_uint(f);
  return (b & 0x80000000u) ? ~b : (b | 0x80000000u);
}
__device__ __forceinline__ float fdec(unsigned u) {
  return (u & 0x80000000u) ? __uint_as_float(u & 0x7fffffffu) : __uint_as_float(~u);
}

// ---- per-column mean/var partials (grid MUST be 256 blocks; blockDim == C) ----
// Also casts x -> bf16 (covers every element exactly once).
__global__ void colstats_f32_kernel(const float* __restrict__ X, int M,
                                    float* __restrict__ ps, float* __restrict__ pss,
                                    unsigned short* __restrict__ xb) {
  int C = blockDim.x, c = threadIdx.x;
  float s = 0.f, ss = 0.f;
  for (int r = blockIdx.x; r < M; r += 256) {
    float v = X[(size_t)r * C + c];
    s += v; ss += v * v;
    xb[(size_t)r * C + c] = f2b(v);
  }
  ps[blockIdx.x * 256 + c] = s;
  pss[blockIdx.x * 256 + c] = ss;
}

__global__ void colstats_bf16_kernel(const unsigned short* __restrict__ X, int M,
                                     float* __restrict__ ps, float* __restrict__ pss) {
  int C = blockDim.x, c = threadIdx.x;
  float s = 0.f, ss = 0.f;
  for (int r = blockIdx.x; r < M; r += 256) {
    float v = b2f(X[(size_t)r * C + c]);
    s += v; ss += v * v;
  }
  ps[blockIdx.x * 256 + c] = s;
  pss[blockIdx.x * 256 + c] = ss;
}

// one block per channel; 64 threads reduce the 256 partials
__global__ void finalize_stats(const float* __restrict__ ps, const float* __restrict__ pss,
                               const float* __restrict__ g, const float* __restrict__ b,
                               float invM, float* __restrict__ scale, float* __restrict__ shift) {
  int c = blockIdx.x, t = threadIdx.x;
  float s = 0.f, ss = 0.f;
#pragma unroll
  for (int k = 0; k < 4; ++k) {
    s  += ps[(t + k * 64) * 256 + c];
    ss += pss[(t + k * 64) * 256 + c];
  }
#pragma unroll
  for (int off = 32; off; off >>= 1) {
    s += __shfl_xor(s, off);
    ss += __shfl_xor(ss, off);
  }
  if (t == 0) {
    float m = s * invM;
    float v = ss * invM - m * m;
    float sc = g[c] * rsqrtf(v + 1e-5f);
    scale[c] = sc;
    shift[c] = b[c] - m * sc;
  }
}

// ---- weight fold: Wt[n][k] = bf16(scale[k]*W[k][n]); bias2[n] = bias_in[n] + sum_k shift[k]*W[k][n]
// Also inits the 4-slot global als-max accumulator (ordered-uint).
__global__ __launch_bounds__(256) void wfold_kernel(const float* __restrict__ W,
    const float* __restrict__ scale, const float* __restrict__ shift,
    const float* __restrict__ bias_in, unsigned short* __restrict__ Wt,
    float* __restrict__ bias2, unsigned* __restrict__ gmaxu, int K) {
  int n = blockIdx.x;   // 256
  int t = threadIdx.x;  // 256
  if (n == 0 && t < 4) gmaxu[t] = fenc(-1e30f);
  float part = 0.f;
  if (t < K) {
    float wv = W[(size_t)t * 256 + n];
    Wt[(size_t)n * K + t] = f2b(scale[t] * wv);
    part = shift[t] * wv;
  }
  __shared__ float red[256];
  red[t] = part;
  __syncthreads();
  if (t < 128) red[t] += red[t + 128];
  __syncthreads();
  if (t < 64) {
    float s = red[t] + red[t + 64];
#pragma unroll
    for (int off = 32; off; off >>= 1) s += __shfl_xor(s, off);
    if (t == 0) bias2[n] = (bias_in ? bias_in[n] : 0.f) + s;
  }
}

// ---- pure-bf16 MFMA GEMM + fused attention logits (direct store, no atomics) ----
// C = [relu]( A @ Wt^T + bias2 ); tile 128x128x32, 4 waves (2x2), N fixed 256.
// Wave wn owns head (bn>>6)+wn; als/ald stored directly; per-wave als-max
// feeds one atomicMax into gmaxu[head].
__global__ __launch_bounds__(256) void gemm_bf16_kernel(
    const unsigned short* __restrict__ Ab, const unsigned short* __restrict__ Wt,
    const float* __restrict__ bias2, unsigned short* __restrict__ Cb,
    int M, int K, int do_relu,
    float* __restrict__ als, float* __restrict__ ald,
    const float* __restrict__ asrc, const float* __restrict__ adst,
    unsigned* __restrict__ gmaxu) {
  __shared__ unsigned short Am[128][40];  // rows padded to 80B (16B aligned)
  __shared__ unsigned short Bn[128][40];
  int tid = threadIdx.x;
  int lane = tid & 63, wid = tid >> 6;
  int wm = wid >> 1, wn = wid & 1;
  int bm = blockIdx.x * 128, bn = blockIdx.y * 128;
  int lrow = lane & 15, lkh = (lane >> 4) * 8;
  int sr = tid >> 2;   // 0..63
  int ssg = tid & 3;   // 16B segment in k (8 bf16)

  f32x4 acc[4][4] = {};

  for (int k0 = 0; k0 < K; k0 += 32) {
    {
      int ra = min(bm + sr, M - 1);
      uint4 v0 = *reinterpret_cast<const uint4*>(Ab + (size_t)ra * K + k0 + ssg * 8);
      *reinterpret_cast<uint4*>(&Am[sr][ssg * 8]) = v0;
      int rb = min(bm + sr + 64, M - 1);
      uint4 v1 = *reinterpret_cast<const uint4*>(Ab + (size_t)rb * K + k0 + ssg * 8);
      *reinterpret_cast<uint4*>(&Am[sr + 64][ssg * 8]) = v1;
      uint4 w0 = *reinterpret_cast<const uint4*>(Wt + (size_t)(bn + sr) * K + k0 + ssg * 8);
      *reinterpret_cast<uint4*>(&Bn[sr][ssg * 8]) = w0;
      uint4 w1 = *reinterpret_cast<const uint4*>(Wt + (size_t)(bn + sr + 64) * K + k0 + ssg * 8);
      *reinterpret_cast<uint4*>(&Bn[sr + 64][ssg * 8]) = w1;
    }
    __syncthreads();
    bf16x8 af[4], bfr[4];
#pragma unroll
    for (int i = 0; i < 4; ++i)
      af[i] = *reinterpret_cast<const bf16x8*>(&Am[wm * 64 + i * 16 + lrow][lkh]);
#pragma unroll
    for (int j = 0; j < 4; ++j)
      bfr[j] = *reinterpret_cast<const bf16x8*>(&Bn[wn * 64 + j * 16 + lrow][lkh]);
#pragma unroll
    for (int i = 0; i < 4; ++i)
#pragma unroll
      for (int j = 0; j < 4; ++j)
        acc[i][j] = __builtin_amdgcn_mfma_f32_16x16x32_bf16(af[i], bfr[j], acc[i][j], 0, 0, 0);
    __syncthreads();
  }

  int r4 = (lane >> 4) * 4;
  bool att = (als != nullptr);
  int head = (bn >> 6) + wn;
  float bv[4], asv[4], adv[4];
#pragma unroll
  for (int j = 0; j < 4; ++j) {
    int colv = bn + wn * 64 + j * 16 + lrow;
    bv[j] = bias2[colv];
    if (att) { asv[j] = asrc[colv]; adv[j] = adst[colv]; }
  }
  float wmax = -1e30f;
#pragma unroll
  for (int i = 0; i < 4; ++i) {
#pragma unroll
    for (int r = 0; r < 4; ++r) {
      int row = bm + wm * 64 + i * 16 + r4 + r;
      float ps = 0.f, pd = 0.f;
#pragma unroll
      for (int j = 0; j < 4; ++j) {
        int colv = bn + wn * 64 + j * 16 + lrow;
        float v = acc[i][j][r] + bv[j];
        if (do_relu) v = fmaxf(v, 0.f);
        if (row < M) Cb[(size_t)row * HID + colv] = f2b(v);
        if (att) { ps += v * asv[j]; pd += v * adv[j]; }
      }
      if (att) {
#pragma unroll
        for (int off = 1; off < 16; off <<= 1) {
          ps += __shfl_xor(ps, off);
          pd += __shfl_xor(pd, off);
        }
        if (row < M) {
          wmax = fmaxf(wmax, ps);
          if (lrow == 0) {
            als[row * 4 + head] = ps;
            ald[row * 4 + head] = pd;
          }
        }
      }
    }
  }
  if (att) {
    wmax = fmaxf(wmax, __shfl_xor(wmax, 16));
    wmax = fmaxf(wmax, __shfl_xor(wmax, 32));
    if (lane == 0) atomicMax(&gmaxu[head], fenc(wmax));
  }
}

// ---- CSR build (dst identical across layers; build once) ----
__device__ __forceinline__ void edge_sd(const int* __restrict__ ei, int e, int& s, int& d) {
  if (e < NE) { s = ei[e]; d = ei[NE + e]; }
  else        { s = e - NE; d = s; }
}

__global__ void zero_int_kernel(int* __restrict__ p, int n) {
  int i = blockIdx.x * blockDim.x + threadIdx.x;
  if (i < n) p[i] = 0;
}

__global__ void hist_kernel(const int* __restrict__ ei, int* __restrict__ deg) {
  int e = blockIdx.x * blockDim.x + threadIdx.x;
  if (e >= NTOT) return;
  int s, d; edge_sd(ei, e, s, d);
  atomicAdd(&deg[d], 1);
}

__global__ __launch_bounds__(1024) void scan_kernel(const int* __restrict__ deg,
                                                    int* __restrict__ rp,
                                                    int* __restrict__ cursor) {
  __shared__ int part[1024];
  int t = threadIdx.x;
  const int C = (NN + 1023) / 1024;
  int base = t * C;
  int s = 0;
  for (int i = 0; i < C; ++i) {
    int idx = base + i;
    if (idx < NN) s += deg[idx];
  }
  part[t] = s;
  __syncthreads();
  for (int off = 1; off < 1024; off <<= 1) {
    int u = (t >= off) ? part[t - off] : 0;
    __syncthreads();
    part[t] += u;
    __syncthreads();
  }
  int run = part[t] - s;
  for (int i = 0; i < C; ++i) {
    int idx = base + i;
    if (idx < NN) {
      rp[idx] = run;
      cursor[idx] = run;
      run += deg[idx];
    }
  }
  if (t == 1023) rp[NN] = part[1023];
}

__global__ void scatter_kernel(const int* __restrict__ ei, int* __restrict__ cursor,
                               int* __restrict__ col) {
  int e = blockIdx.x * blockDim.x + threadIdx.x;
  if (e >= NTOT) return;
  int s, d; edge_sd(ei, e, s, d);
  int pos = atomicAdd(&cursor[d], 1);
  col[pos] = s;
}

// ---- fused GAT aggregation: ONE WAVE PER NODE, single pass ----
// Stability bound m = lrelu(gmax_als[h] + ald[n][h]) >= all edge logits of node
// (lrelu monotonic), so no per-node max pass is needed; shift cancels in p/s.
// Gather: half-waves process 2 edges at once; each lane loads uint4 (8 ch).
__global__ __launch_bounds__(256) void gat_agg_kernel(
    const int* __restrict__ rp, const int* __restrict__ col,
    const float* __restrict__ als, const float* __restrict__ ald,
    const unsigned* __restrict__ gmaxu,
    const unsigned short* __restrict__ xp, const float* __restrict__ bias,
    unsigned short* __restrict__ out) {
  int wv = threadIdx.x >> 6, lane = threadIdx.x & 63;
  int n = blockIdx.x * 4 + wv;
  if (n >= NN) return;
  int beg = rp[n], deg = rp[n + 1] - beg;
  int hh = lane & 3;       // head this lane computes coefs for
  int jof = lane >> 2;     // edge slot within a 16-edge round
  float aldh = ald[n * 4 + hh];
  float mh = fdec(gmaxu[hh]) + aldh;
  mh = mh > 0.f ? mh : 0.2f * mh;   // upper bound of lrelu(logit) for this node/head
  int li = lane & 31, half = lane >> 5;
  int c0 = li * 8;         // this lane's 8 output channels
  int hme = li >> 3;       // head of those channels
  float a0 = 0.f, a1 = 0.f, a2 = 0.f, a3 = 0.f;
  float a4 = 0.f, a5 = 0.f, a6 = 0.f, a7 = 0.f;
  float ss = 0.f;
  int full = deg & ~15, rem = deg - full;
  for (int r0 = 0; r0 < full; r0 += 16) {
    int sreg = col[beg + r0 + jof];
    float l = als[sreg * 4 + hh] + aldh;
    l = l > 0.f ? l : 0.2f * l;
    float cf = __expf(l - mh);
    ss += cf;
#pragma unroll
    for (int t = 0; t < 8; ++t) {
      int j2 = 2 * t + half;
      int s = __shfl(sreg, j2 << 2);
      float c = __shfl(cf, (j2 << 2) | hme);
      uint4 w = *reinterpret_cast<const uint4*>(xp + (size_t)s * HID + c0);
      a0 += c * b2f((unsigned short)(w.x & 0xffffu));
      a1 += c * b2f((unsigned short)(w.x >> 16));
      a2 += c * b2f((unsigned short)(w.y & 0xffffu));
      a3 += c * b2f((unsigned short)(w.y >> 16));
      a4 += c * b2f((unsigned short)(w.z & 0xffffu));
      a5 += c * b2f((unsigned short)(w.z >> 16));
      a6 += c * b2f((unsigned short)(w.w & 0xffffu));
      a7 += c * b2f((unsigned short)(w.w >> 16));
    }
  }
  if (rem) {
    int sreg = 0;
    float cf = 0.f;
    if (jof < rem) {
      sreg = col[beg + full + jof];
      float l = als[sreg * 4 + hh] + aldh;
      l = l > 0.f ? l : 0.2f * l;
      cf = __expf(l - mh);
      ss += cf;
    }
    int pairs = (rem + 1) >> 1;
    for (int t = 0; t < pairs; ++t) {
      int j2 = 2 * t + half;
      int s = __shfl(sreg, j2 << 2);       // cf==0 for invalid slots -> contributes 0
      float c = __shfl(cf, (j2 << 2) | hme);
      uint4 w = *reinterpret_cast<const uint4*>(xp + (size_t)s * HID + c0);
      a0 += c * b2f((unsigned short)(w.x & 0xffffu));
      a1 += c * b2f((unsigned short)(w.x >> 16));
      a2 += c * b2f((unsigned short)(w.y & 0xffffu));
      a3 += c * b2f((unsigned short)(w.y >> 16));
      a4 += c * b2f((unsigned short)(w.z & 0xffffu));
      a5 += c * b2f((unsigned short)(w.z >> 16));
      a6 += c * b2f((unsigned short)(w.w & 0xffffu));
      a7 += c * b2f((unsigned short)(w.w >> 16));
    }
  }
  // merge the two half-wave partials (edges split even/odd)
  a0 += __shfl_xor(a0, 32); a1 += __shfl_xor(a1, 32);
  a2 += __shfl_xor(a2, 32); a3 += __shfl_xor(a3, 32);
  a4 += __shfl_xor(a4, 32); a5 += __shfl_xor(a5, 32);
  a6 += __shfl_xor(a6, 32); a7 += __shfl_xor(a7, 32);
#pragma unroll
  for (int off = 4; off < 64; off <<= 1) ss += __shfl_xor(ss, off);
  float inv = 1.0f / __shfl(ss, hme);   // lane hme holds head-hme total
  if (half == 0) {
    float4 b0 = *reinterpret_cast<const float4*>(bias + c0);
    float4 b1 = *reinterpret_cast<const float4*>(bias + c0 + 4);
    uint4 o;
    o.x = (unsigned)f2b(fmaxf(a0 * inv + b0.x, 0.f)) | ((unsigned)f2b(fmaxf(a1 * inv + b0.y, 0.f)) << 16);
    o.y = (unsigned)f2b(fmaxf(a2 * inv + b0.z, 0.f)) | ((unsigned)f2b(fmaxf(a3 * inv + b0.w, 0.f)) << 16);
    o.z = (unsigned)f2b(fmaxf(a4 * inv + b1.x, 0.f)) | ((unsigned)f2b(fmaxf(a5 * inv + b1.y, 0.f)) << 16);
    o.w = (unsigned)f2b(fmaxf(a6 * inv + b1.z, 0.f)) | ((unsigned)f2b(fmaxf(a7 * inv + b1.w, 0.f)) << 16);
    *reinterpret_cast<uint4*>(out + (size_t)n * HID + c0) = o;
  }
}

// ---- pool: 256 blocks over contiguous node ranges, boundary atomics ----
__global__ void pool_kernel(const unsigned short* __restrict__ h, const int* __restrict__ batch,
                            float* __restrict__ g) {
  const int ROWS = (NN + 255) / 256;
  int r0 = blockIdx.x * ROWS;
  int r1 = min(r0 + ROWS, NN);
  if (r0 >= r1) return;
  int c = threadIdx.x;
  int cur = batch[r0];
  float acc = 0.f;
  for (int r = r0; r < r1; ++r) {
    int b = batch[r];
    if (b != cur) {
      atomicAdd(&g[(size_t)cur * HID + c], acc);
      acc = 0.f;
      cur = b;
    }
    acc += b2f(h[(size_t)r * HID + c]);
  }
  atomicAdd(&g[(size_t)cur * HID + c], acc);
}

// ---- tail: BN (redundant per-block stats, L2-hot) fused into consumers ----
__global__ void fc_bn_kernel(const float* __restrict__ gin, const float* __restrict__ gamma,
                             const float* __restrict__ beta, const float* __restrict__ W,
                             const float* __restrict__ b, float* __restrict__ gout) {
  __shared__ float row[HID];
  int g = blockIdx.x, t = threadIdx.x;  // 256
  float s = 0.f, ss = 0.f;
  for (int r = 0; r < NG; ++r) {
    float v = gin[r * HID + t];
    s += v; ss += v * v;
  }
  float mn = s / NG, var = ss / NG - mn * mn;
  float sc = gamma[t] * rsqrtf(var + 1e-5f);
  float sh = beta[t] - mn * sc;
  row[t] = gin[g * HID + t] * sc + sh;
  __syncthreads();
  float acc = b[t];
  for (int k = 0; k < HID; ++k) acc += row[k] * W[k * HID + t];
  gout[g * HID + t] = fmaxf(acc, 0.f);
}

__global__ void cls_bn_kernel(const float* __restrict__ gin, const float* __restrict__ gamma,
                              const float* __restrict__ beta, const float* __restrict__ W,
                              const float* __restrict__ b, float* __restrict__ out) {
  __shared__ float row[HID];
  __shared__ float logits[NCLS];
  int g = blockIdx.x, t = threadIdx.x;
  float s = 0.f, ss = 0.f;
  for (int r = 0; r < NG; ++r) {
    float v = gin[r * HID + t];
    s += v; ss += v * v;
  }
  float mn = s / NG, var = ss / NG - mn * mn;
  float sc = gamma[t] * rsqrtf(var + 1e-5f);
  float sh = beta[t] - mn * sc;
  row[t] = gin[g * HID + t] * sc + sh;
  __syncthreads();
  if (t < NCLS) {
    float a = b[t];
    for (int k = 0; k < HID; ++k) a += row[k] * W[k * NCLS + t];
    logits[t] = a;
  }
  __syncthreads();
  if (t == 0) {
    float mxv = -1e30f;
    for (int i = 0; i < NCLS; ++i) mxv = fmaxf(mxv, logits[i]);
    float se = 0.f;
    for (int i = 0; i < NCLS; ++i) se += expf(logits[i] - mxv);
    float lse = mxv + logf(se);
    for (int i = 0; i < NCLS; ++i) out[g * NCLS + i] = logits[i] - lse;
  }
}

extern "C" void kernel_launch(void* const* d_in, const int* in_sizes, int n_in,
                              void* d_out, int out_size, void* d_ws, size_t ws_size,
                              hipStream_t stream) {
  const float* x        = (const float*)d_in[0];
  const int*   ei       = (const int*)d_in[1];
  const int*   batch    = (const int*)d_in[2];
  const float* bn_feat_g = (const float*)d_in[3];
  const float* bn_feat_b = (const float*)d_in[4];
  const float* W_feat   = (const float*)d_in[5];
  const float* b_feat   = (const float*)d_in[6];
  const float* bns_g    = (const float*)d_in[7];
  const float* bns_b    = (const float*)d_in[8];
  const float* Wg       = (const float*)d_in[9];
  const float* att_src  = (const float*)d_in[10];
  const float* att_dst  = (const float*)d_in[11];
  const float* gat_b    = (const float*)d_in[12];
  const float* bn_fc_g  = (const float*)d_in[13];
  const float* bn_fc_b  = (const float*)d_in[14];
  const float* W_fc     = (const float*)d_in[15];
  const float* b_fc     = (const float*)d_in[16];
  const float* bn_h_g   = (const float*)d_in[17];
  const float* bn_h_b   = (const float*)d_in[18];
  const float* W_cls    = (const float*)d_in[19];
  const float* b_cls    = (const float*)d_in[20];

  char* ws = (char*)d_ws;
  size_t off = 0;
  auto alloc = [&](size_t bytes) -> void* {
    void* p = ws + off;
    off += (bytes + 255) & ~(size_t)255;
    return p;
  };
  float* psum   = (float*)alloc(256 * 256 * 4);
  float* psumsq = (float*)alloc(256 * 256 * 4);
  float* scale  = (float*)alloc(HID * 4);
  float* shift  = (float*)alloc(HID * 4);
  float* bias2  = (float*)alloc(HID * 4);
  unsigned* gmaxu = (unsigned*)alloc(4 * 4);
  float* als    = (float*)alloc((size_t)NN * 4 * 4);
  float* ald    = (float*)alloc((size_t)NN * 4 * 4);
  int*   deg    = (int*)alloc((size_t)NN * 4);
  int*   cursor = (int*)alloc((size_t)NN * 4);
  int*   rp     = (int*)alloc((size_t)(NN + 1) * 4);
  int*   col    = (int*)alloc((size_t)NTOT * 4);
  unsigned short* xb  = (unsigned short*)alloc((size_t)NN * FIN * 2);   // x bf16
  unsigned short* Wft = (unsigned short*)alloc((size_t)HID * FIN * 2);  // folded stage0 W
  unsigned short* Wgt = (unsigned short*)alloc((size_t)HID * HID * 2);  // folded layer W (reused)
  unsigned short* bufA = (unsigned short*)alloc((size_t)NN * HID * 2);  // h (bf16)
  unsigned short* xp   = (unsigned short*)alloc((size_t)NN * HID * 2);  // xp (bf16)
  float* g0     = (float*)alloc((size_t)NG * HID * 4);
  float* g1     = (float*)alloc((size_t)NG * HID * 4);
  (void)ws_size; (void)n_in; (void)in_sizes; (void)out_size;

  const int ETHREADS = 256;
  const int EGRID = (NTOT + ETHREADS - 1) / ETHREADS;

  // ---- CSR build (independent of activations)
  zero_int_kernel<<<(NN + 255) / 256, 256, 0, stream>>>(deg, NN);
  hist_kernel<<<EGRID, ETHREADS, 0, stream>>>(ei, deg);
  scan_kernel<<<1, 1024, 0, stream>>>(deg, rp, cursor);
  scatter_kernel<<<EGRID, ETHREADS, 0, stream>>>(ei, cursor, col);

  // ---- stage 0: h = bf16(relu( xb @ fold(W_feat) + bias2 ))  (cast fused in colstats)
  colstats_f32_kernel<<<256, FIN, 0, stream>>>(x, NN, psum, psumsq, xb);
  finalize_stats<<<FIN, 64, 0, stream>>>(psum, psumsq, bn_feat_g, bn_feat_b,
                                         1.0f / NN, scale, shift);
  wfold_kernel<<<HID, 256, 0, stream>>>(W_feat, scale, shift, b_feat, Wft, bias2, gmaxu, FIN);
  gemm_bf16_kernel<<<dim3((NN + 127) / 128, 2), 256, 0, stream>>>(
      xb, Wft, bias2, bufA, NN, FIN, 1, nullptr, nullptr, nullptr, nullptr, gmaxu);

  // ---- 3 GAT layers
  for (int i = 0; i < 3; ++i) {
    colstats_bf16_kernel<<<256, HID, 0, stream>>>(bufA, NN, psum, psumsq);
    finalize_stats<<<HID, 64, 0, stream>>>(psum, psumsq, bns_g + i * HID, bns_b + i * HID,
                                           1.0f / NN, scale, shift);
    wfold_kernel<<<HID, 256, 0, stream>>>(Wg + (size_t)i * HID * HID, scale, shift,
                                          nullptr, Wgt, bias2, gmaxu, HID);
    // xp = bf16(BN(h)@Wg[i]) with fused, direct-store attention logits + global als max
    gemm_bf16_kernel<<<dim3((NN + 127) / 128, 2), 256, 0, stream>>>(
        bufA, Wgt, bias2, xp, NN, HID, 0, als, ald,
        att_src + i * HID, att_dst + i * HID, gmaxu);
    gat_agg_kernel<<<(NN + 3) / 4, 256, 0, stream>>>(rp, col, als, ald, gmaxu, xp,
                                                     gat_b + i * HID, bufA);
  }

  // ---- pool + fused tail
  hipMemsetAsync(g0, 0, (size_t)NG * HID * 4, stream);
  pool_kernel<<<256, HID, 0, stream>>>(bufA, batch, g0);
  fc_bn_kernel<<<NG, HID, 0, stream>>>(g0, bn_fc_g, bn_fc_b, W_fc, b_fc, g1);
  cls_bn_kernel<<<NG, HID, 0, stream>>>(g1, bn_h_g, bn_h_b, W_cls, b_cls, (float*)d_out);
}

// Round 10
// 404.605 us; speedup vs baseline: 1.0604x; 1.0604x over previous
//
#include <hip/hip_runtime.h>

// Problem constants (fixed by reference)
constexpr int NN   = 20000;          // nodes
constexpr int NE   = 320000;         // edges (before self-loops)
constexpr int NTOT = NE + NN;        // edges incl self-loops
constexpr int FIN  = 128;
constexpr int HID  = 256;
constexpr int NG   = 128;            // graphs
constexpr int NCLS = 10;

typedef __bf16 bf16x8 __attribute__((ext_vector_type(8)));
typedef float  f32x4  __attribute__((ext_vector_type(4)));

__device__ __forceinline__ unsigned short f2b(float f) {
  unsigned u = __float_as_uint(f);
  unsigned r = (u + 0x7fffu + ((u >> 16) & 1u)) >> 16;
  return (unsigned short)r;
}
__device__ __forceinline__ float b2f(unsigned short h) {
  return __uint_as_float((unsigned)h << 16);
}

// ---- per-column mean/var partials (grid MUST be 256 blocks; blockDim == C) ----
// Also casts x -> bf16 (covers every element exactly once).
__global__ void colstats_f32_kernel(const float* __restrict__ X, int M,
                                    float* __restrict__ ps, float* __restrict__ pss,
                                    unsigned short* __restrict__ xb) {
  int C = blockDim.x, c = threadIdx.x;
  float s = 0.f, ss = 0.f;
  for (int r = blockIdx.x; r < M; r += 256) {
    float v = X[(size_t)r * C + c];
    s += v; ss += v * v;
    xb[(size_t)r * C + c] = f2b(v);
  }
  ps[blockIdx.x * 256 + c] = s;
  pss[blockIdx.x * 256 + c] = ss;
}

__global__ void colstats_bf16_kernel(const unsigned short* __restrict__ X, int M,
                                     float* __restrict__ ps, float* __restrict__ pss) {
  int C = blockDim.x, c = threadIdx.x;
  float s = 0.f, ss = 0.f;
  for (int r = blockIdx.x; r < M; r += 256) {
    float v = b2f(X[(size_t)r * C + c]);
    s += v; ss += v * v;
  }
  ps[blockIdx.x * 256 + c] = s;
  pss[blockIdx.x * 256 + c] = ss;
}

// one block per channel; 64 threads reduce the 256 partials
__global__ void finalize_stats(const float* __restrict__ ps, const float* __restrict__ pss,
                               const float* __restrict__ g, const float* __restrict__ b,
                               float invM, float* __restrict__ scale, float* __restrict__ shift) {
  int c = blockIdx.x, t = threadIdx.x;
  float s = 0.f, ss = 0.f;
#pragma unroll
  for (int k = 0; k < 4; ++k) {
    s  += ps[(t + k * 64) * 256 + c];
    ss += pss[(t + k * 64) * 256 + c];
  }
#pragma unroll
  for (int off = 32; off; off >>= 1) {
    s += __shfl_xor(s, off);
    ss += __shfl_xor(ss, off);
  }
  if (t == 0) {
    float m = s * invM;
    float v = ss * invM - m * m;
    float sc = g[c] * rsqrtf(v + 1e-5f);
    scale[c] = sc;
    shift[c] = b[c] - m * sc;
  }
}

// ---- weight fold: Wt[n][k] = bf16(scale[k]*W[k][n]); bias2[n] = bias_in[n] + sum_k shift[k]*W[k][n]
__global__ __launch_bounds__(256) void wfold_kernel(const float* __restrict__ W,
    const float* __restrict__ scale, const float* __restrict__ shift,
    const float* __restrict__ bias_in, unsigned short* __restrict__ Wt,
    float* __restrict__ bias2, int K) {
  int n = blockIdx.x;   // 256
  int t = threadIdx.x;  // 256
  float part = 0.f;
  if (t < K) {
    float wv = W[(size_t)t * 256 + n];
    Wt[(size_t)n * K + t] = f2b(scale[t] * wv);
    part = shift[t] * wv;
  }
  __shared__ float red[256];
  red[t] = part;
  __syncthreads();
  if (t < 128) red[t] += red[t + 128];
  __syncthreads();
  if (t < 64) {
    float s = red[t] + red[t + 64];
#pragma unroll
    for (int off = 32; off; off >>= 1) s += __shfl_xor(s, off);
    if (t == 0) bias2[n] = (bias_in ? bias_in[n] : 0.f) + s;
  }
}

// ---- pure-bf16 MFMA GEMM + fused attention logits (direct store, no atomics) ----
// C = [relu]( A @ Wt^T + bias2 ); tile 128x128x32, 4 waves (2x2), N fixed 256.
// Block cols [bn,bn+128) = heads (bn>>6)+0 and +1; wave wn owns head (bn>>6)+wn,
// so als[row,head]/ald[row,head] are computed completely within one wave.
__global__ __launch_bounds__(256) void gemm_bf16_kernel(
    const unsigned short* __restrict__ Ab, const unsigned short* __restrict__ Wt,
    const float* __restrict__ bias2, unsigned short* __restrict__ Cb,
    int M, int K, int do_relu,
    float* __restrict__ als, float* __restrict__ ald,
    const float* __restrict__ asrc, const float* __restrict__ adst) {
  __shared__ unsigned short Am[128][40];  // rows padded to 80B (16B aligned)
  __shared__ unsigned short Bn[128][40];
  int tid = threadIdx.x;
  int lane = tid & 63, wid = tid >> 6;
  int wm = wid >> 1, wn = wid & 1;
  int bm = blockIdx.x * 128, bn = blockIdx.y * 128;
  int lrow = lane & 15, lkh = (lane >> 4) * 8;
  int sr = tid >> 2;   // 0..63
  int ssg = tid & 3;   // 16B segment in k (8 bf16)

  f32x4 acc[4][4] = {};

  for (int k0 = 0; k0 < K; k0 += 32) {
    {
      int ra = min(bm + sr, M - 1);
      uint4 v0 = *reinterpret_cast<const uint4*>(Ab + (size_t)ra * K + k0 + ssg * 8);
      *reinterpret_cast<uint4*>(&Am[sr][ssg * 8]) = v0;
      int rb = min(bm + sr + 64, M - 1);
      uint4 v1 = *reinterpret_cast<const uint4*>(Ab + (size_t)rb * K + k0 + ssg * 8);
      *reinterpret_cast<uint4*>(&Am[sr + 64][ssg * 8]) = v1;
      uint4 w0 = *reinterpret_cast<const uint4*>(Wt + (size_t)(bn + sr) * K + k0 + ssg * 8);
      *reinterpret_cast<uint4*>(&Bn[sr][ssg * 8]) = w0;
      uint4 w1 = *reinterpret_cast<const uint4*>(Wt + (size_t)(bn + sr + 64) * K + k0 + ssg * 8);
      *reinterpret_cast<uint4*>(&Bn[sr + 64][ssg * 8]) = w1;
    }
    __syncthreads();
    bf16x8 af[4], bfr[4];
#pragma unroll
    for (int i = 0; i < 4; ++i)
      af[i] = *reinterpret_cast<const bf16x8*>(&Am[wm * 64 + i * 16 + lrow][lkh]);
#pragma unroll
    for (int j = 0; j < 4; ++j)
      bfr[j] = *reinterpret_cast<const bf16x8*>(&Bn[wn * 64 + j * 16 + lrow][lkh]);
#pragma unroll
    for (int i = 0; i < 4; ++i)
#pragma unroll
      for (int j = 0; j < 4; ++j)
        acc[i][j] = __builtin_amdgcn_mfma_f32_16x16x32_bf16(af[i], bfr[j], acc[i][j], 0, 0, 0);
    __syncthreads();
  }

  int r4 = (lane >> 4) * 4;
  bool att = (als != nullptr);
  int head = (bn >> 6) + wn;
  float bv[4], asv[4], adv[4];
#pragma unroll
  for (int j = 0; j < 4; ++j) {
    int colv = bn + wn * 64 + j * 16 + lrow;
    bv[j] = bias2[colv];
    if (att) { asv[j] = asrc[colv]; adv[j] = adst[colv]; }
  }
#pragma unroll
  for (int i = 0; i < 4; ++i) {
#pragma unroll
    for (int r = 0; r < 4; ++r) {
      int row = bm + wm * 64 + i * 16 + r4 + r;
      float ps = 0.f, pd = 0.f;
#pragma unroll
      for (int j = 0; j < 4; ++j) {
        int colv = bn + wn * 64 + j * 16 + lrow;
        float v = acc[i][j][r] + bv[j];
        if (do_relu) v = fmaxf(v, 0.f);
        if (row < M) Cb[(size_t)row * HID + colv] = f2b(v);
        if (att) { ps += v * asv[j]; pd += v * adv[j]; }
      }
      if (att) {
#pragma unroll
        for (int off = 1; off < 16; off <<= 1) {
          ps += __shfl_xor(ps, off);
          pd += __shfl_xor(pd, off);
        }
        if (lrow == 0 && row < M) {
          als[row * 4 + head] = ps;
          ald[row * 4 + head] = pd;
        }
      }
    }
  }
}

// ---- CSR build (dst identical across layers; build once) ----
__device__ __forceinline__ void edge_sd(const int* __restrict__ ei, int e, int& s, int& d) {
  if (e < NE) { s = ei[e]; d = ei[NE + e]; }
  else        { s = e - NE; d = s; }
}

__global__ void hist_kernel(const int* __restrict__ ei, int* __restrict__ deg) {
  int e = blockIdx.x * blockDim.x + threadIdx.x;
  if (e >= NTOT) return;
  int s, d; edge_sd(ei, e, s, d);
  atomicAdd(&deg[d], 1);
}

__global__ __launch_bounds__(1024) void scan_kernel(const int* __restrict__ deg,
                                                    int* __restrict__ rp,
                                                    int* __restrict__ cursor) {
  __shared__ int part[1024];
  int t = threadIdx.x;
  const int C = (NN + 1023) / 1024;
  int base = t * C;
  int s = 0;
  for (int i = 0; i < C; ++i) {
    int idx = base + i;
    if (idx < NN) s += deg[idx];
  }
  part[t] = s;
  __syncthreads();
  for (int off = 1; off < 1024; off <<= 1) {
    int u = (t >= off) ? part[t - off] : 0;
    __syncthreads();
    part[t] += u;
    __syncthreads();
  }
  int run = part[t] - s;
  for (int i = 0; i < C; ++i) {
    int idx = base + i;
    if (idx < NN) {
      rp[idx] = run;
      cursor[idx] = run;
      run += deg[idx];
    }
  }
  if (t == 1023) rp[NN] = part[1023];
}

__global__ void scatter_kernel(const int* __restrict__ ei, int* __restrict__ cursor,
                               int* __restrict__ col) {
  int e = blockIdx.x * blockDim.x + threadIdx.x;
  if (e >= NTOT) return;
  int s, d; edge_sd(ei, e, s, d);
  int pos = atomicAdd(&cursor[d], 1);
  col[pos] = s;
}

// ---- fused GAT aggregation: ONE WAVE PER NODE, single-exp, unrolled rounds ----
__global__ __launch_bounds__(256) void gat_agg_kernel(
    const int* __restrict__ rp, const int* __restrict__ col,
    const float* __restrict__ als, const float* __restrict__ ald,
    const unsigned short* __restrict__ xp, const float* __restrict__ bias,
    unsigned short* __restrict__ out) {
  int wv = threadIdx.x >> 6, lane = threadIdx.x & 63;
  int n = blockIdx.x * 4 + wv;
  if (n >= NN) return;
  int beg = rp[n], deg = rp[n + 1] - beg;
  int hh = lane & 3;       // head this lane computes logits for
  int jof = lane >> 2;     // edge offset within a 16-edge round
  float aldh = ald[n * 4 + hh];
  int full = deg & ~15;
  int rem = deg - full;
  // phase A: global max per head
  float m = -1e30f;
  for (int r0 = 0; r0 < full; r0 += 16) {
    int s = col[beg + r0 + jof];
    float l = als[s * 4 + hh] + aldh;
    l = l > 0.f ? l : 0.2f * l;
    m = fmaxf(m, l);
  }
  if (jof < rem) {
    int s = col[beg + full + jof];
    float l = als[s * 4 + hh] + aldh;
    l = l > 0.f ? l : 0.2f * l;
    m = fmaxf(m, l);
  }
#pragma unroll
  for (int off = 4; off < 64; off <<= 1) m = fmaxf(m, __shfl_xor(m, off));
  // phase B: exp + unnormalized gather + ssum
  int c0 = lane * 4;       // this lane's 4 output channels
  int hme = lane >> 4;     // head of those channels
  float ss = 0.f;
  float a0 = 0.f, a1 = 0.f, a2 = 0.f, a3 = 0.f;
  for (int r0 = 0; r0 < full; r0 += 16) {
    int sreg = col[beg + r0 + jof];
    float l = als[sreg * 4 + hh] + aldh;
    l = l > 0.f ? l : 0.2f * l;
    float cf = __expf(l - m);
    ss += cf;
#pragma unroll
    for (int jj = 0; jj < 16; ++jj) {
      int s = __shfl(sreg, jj << 2);
      float c = __shfl(cf, (jj << 2) | hme);
      uint2 w = *reinterpret_cast<const uint2*>(xp + (size_t)s * HID + c0);
      a0 += c * b2f((unsigned short)(w.x & 0xffff));
      a1 += c * b2f((unsigned short)(w.x >> 16));
      a2 += c * b2f((unsigned short)(w.y & 0xffff));
      a3 += c * b2f((unsigned short)(w.y >> 16));
    }
  }
  if (rem) {
    int sreg = 0;
    float cf = 0.f;
    if (jof < rem) {
      sreg = col[beg + full + jof];
      float l = als[sreg * 4 + hh] + aldh;
      l = l > 0.f ? l : 0.2f * l;
      cf = __expf(l - m);
      ss += cf;
    }
    for (int jj = 0; jj < rem; ++jj) {
      int s = __shfl(sreg, jj << 2);
      float c = __shfl(cf, (jj << 2) | hme);
      uint2 w = *reinterpret_cast<const uint2*>(xp + (size_t)s * HID + c0);
      a0 += c * b2f((unsigned short)(w.x & 0xffff));
      a1 += c * b2f((unsigned short)(w.x >> 16));
      a2 += c * b2f((unsigned short)(w.y & 0xffff));
      a3 += c * b2f((unsigned short)(w.y >> 16));
    }
  }
#pragma unroll
  for (int off = 4; off < 64; off <<= 1) ss += __shfl_xor(ss, off);
  float inv = 1.0f / __shfl(ss, hme);   // lane hme holds the total for head hme
  float4 bvv = *reinterpret_cast<const float4*>(bias + c0);
  ushort4 o;
  o.x = f2b(fmaxf(a0 * inv + bvv.x, 0.f));
  o.y = f2b(fmaxf(a1 * inv + bvv.y, 0.f));
  o.z = f2b(fmaxf(a2 * inv + bvv.z, 0.f));
  o.w = f2b(fmaxf(a3 * inv + bvv.w, 0.f));
  *reinterpret_cast<ushort4*>(out + (size_t)n * HID + c0) = o;
}

// ---- pool: 256 blocks over contiguous node ranges, boundary atomics ----
__global__ void pool_kernel(const unsigned short* __restrict__ h, const int* __restrict__ batch,
                            float* __restrict__ g) {
  const int ROWS = (NN + 255) / 256;
  int r0 = blockIdx.x * ROWS;
  int r1 = min(r0 + ROWS, NN);
  if (r0 >= r1) return;
  int c = threadIdx.x;
  int cur = batch[r0];
  float acc = 0.f;
  for (int r = r0; r < r1; ++r) {
    int b = batch[r];
    if (b != cur) {
      atomicAdd(&g[(size_t)cur * HID + c], acc);
      acc = 0.f;
      cur = b;
    }
    acc += b2f(h[(size_t)r * HID + c]);
  }
  atomicAdd(&g[(size_t)cur * HID + c], acc);
}

// ---- tail: BN (redundant per-block stats, L2-hot) fused into consumers ----
__global__ void fc_bn_kernel(const float* __restrict__ gin, const float* __restrict__ gamma,
                             const float* __restrict__ beta, const float* __restrict__ W,
                             const float* __restrict__ b, float* __restrict__ gout) {
  __shared__ float row[HID];
  int g = blockIdx.x, t = threadIdx.x;  // 256
  float s = 0.f, ss = 0.f;
  for (int r = 0; r < NG; ++r) {
    float v = gin[r * HID + t];
    s += v; ss += v * v;
  }
  float mn = s / NG, var = ss / NG - mn * mn;
  float sc = gamma[t] * rsqrtf(var + 1e-5f);
  float sh = beta[t] - mn * sc;
  row[t] = gin[g * HID + t] * sc + sh;
  __syncthreads();
  float acc = b[t];
  for (int k = 0; k < HID; ++k) acc += row[k] * W[k * HID + t];
  gout[g * HID + t] = fmaxf(acc, 0.f);
}

__global__ void cls_bn_kernel(const float* __restrict__ gin, const float* __restrict__ gamma,
                              const float* __restrict__ beta, const float* __restrict__ W,
                              const float* __restrict__ b, float* __restrict__ out) {
  __shared__ float row[HID];
  __shared__ float logits[NCLS];
  int g = blockIdx.x, t = threadIdx.x;
  float s = 0.f, ss = 0.f;
  for (int r = 0; r < NG; ++r) {
    float v = gin[r * HID + t];
    s += v; ss += v * v;
  }
  float mn = s / NG, var = ss / NG - mn * mn;
  float sc = gamma[t] * rsqrtf(var + 1e-5f);
  float sh = beta[t] - mn * sc;
  row[t] = gin[g * HID + t] * sc + sh;
  __syncthreads();
  if (t < NCLS) {
    float a = b[t];
    for (int k = 0; k < HID; ++k) a += row[k] * W[k * NCLS + t];
    logits[t] = a;
  }
  __syncthreads();
  if (t == 0) {
    float mxv = -1e30f;
    for (int i = 0; i < NCLS; ++i) mxv = fmaxf(mxv, logits[i]);
    float se = 0.f;
    for (int i = 0; i < NCLS; ++i) se += expf(logits[i] - mxv);
    float lse = mxv + logf(se);
    for (int i = 0; i < NCLS; ++i) out[g * NCLS + i] = logits[i] - lse;
  }
}

extern "C" void kernel_launch(void* const* d_in, const int* in_sizes, int n_in,
                              void* d_out, int out_size, void* d_ws, size_t ws_size,
                              hipStream_t stream) {
  const float* x        = (const float*)d_in[0];
  const int*   ei       = (const int*)d_in[1];
  const int*   batch    = (const int*)d_in[2];
  const float* bn_feat_g = (const float*)d_in[3];
  const float* bn_feat_b = (const float*)d_in[4];
  const float* W_feat   = (const float*)d_in[5];
  const float* b_feat   = (const float*)d_in[6];
  const float* bns_g    = (const float*)d_in[7];
  const float* bns_b    = (const float*)d_in[8];
  const float* Wg       = (const float*)d_in[9];
  const float* att_src  = (const float*)d_in[10];
  const float* att_dst  = (const float*)d_in[11];
  const float* gat_b    = (const float*)d_in[12];
  const float* bn_fc_g  = (const float*)d_in[13];
  const float* bn_fc_b  = (const float*)d_in[14];
  const float* W_fc     = (const float*)d_in[15];
  const float* b_fc     = (const float*)d_in[16];
  const float* bn_h_g   = (const float*)d_in[17];
  const float* bn_h_b   = (const float*)d_in[18];
  const float* W_cls    = (const float*)d_in[19];
  const float* b_cls    = (const float*)d_in[20];

  char* ws = (char*)d_ws;
  size_t off = 0;
  auto alloc = [&](size_t bytes) -> void* {
    void* p = ws + off;
    off += (bytes + 255) & ~(size_t)255;
    return p;
  };
  float* psum   = (float*)alloc(256 * 256 * 4);
  float* psumsq = (float*)alloc(256 * 256 * 4);
  float* scale  = (float*)alloc(HID * 4);
  float* shift  = (float*)alloc(HID * 4);
  float* bias2  = (float*)alloc(HID * 4);
  float* als    = (float*)alloc((size_t)NN * 4 * 4);
  float* ald    = (float*)alloc((size_t)NN * 4 * 4);
  int*   deg    = (int*)alloc((size_t)NN * 4);
  int*   cursor = (int*)alloc((size_t)NN * 4);
  int*   rp     = (int*)alloc((size_t)(NN + 1) * 4);
  int*   col    = (int*)alloc((size_t)NTOT * 4);
  unsigned short* xb  = (unsigned short*)alloc((size_t)NN * FIN * 2);   // x bf16
  unsigned short* Wft = (unsigned short*)alloc((size_t)HID * FIN * 2);  // folded stage0 W
  unsigned short* Wgt = (unsigned short*)alloc((size_t)HID * HID * 2);  // folded layer W (reused)
  unsigned short* bufA = (unsigned short*)alloc((size_t)NN * HID * 2);  // h (bf16)
  unsigned short* xp   = (unsigned short*)alloc((size_t)NN * HID * 2);  // xp (bf16)
  float* g0     = (float*)alloc((size_t)NG * HID * 4);
  float* g1     = (float*)alloc((size_t)NG * HID * 4);
  (void)ws_size; (void)n_in; (void)in_sizes; (void)out_size;

  const int ETHREADS = 256;
  const int EGRID = (NTOT + ETHREADS - 1) / ETHREADS;

  // ---- CSR build (independent of activations)
  hipMemsetAsync(deg, 0, (size_t)NN * 4, stream);
  hist_kernel<<<EGRID, ETHREADS, 0, stream>>>(ei, deg);
  scan_kernel<<<1, 1024, 0, stream>>>(deg, rp, cursor);
  scatter_kernel<<<EGRID, ETHREADS, 0, stream>>>(ei, cursor, col);

  // ---- stage 0: h = bf16(relu( xb @ fold(W_feat) + bias2 ))  (x cast fused in colstats)
  colstats_f32_kernel<<<256, FIN, 0, stream>>>(x, NN, psum, psumsq, xb);
  finalize_stats<<<FIN, 64, 0, stream>>>(psum, psumsq, bn_feat_g, bn_feat_b,
                                         1.0f / NN, scale, shift);
  wfold_kernel<<<HID, 256, 0, stream>>>(W_feat, scale, shift, b_feat, Wft, bias2, FIN);
  gemm_bf16_kernel<<<dim3((NN + 127) / 128, 2), 256, 0, stream>>>(
      xb, Wft, bias2, bufA, NN, FIN, 1, nullptr, nullptr, nullptr, nullptr);

  // ---- 3 GAT layers
  for (int i = 0; i < 3; ++i) {
    colstats_bf16_kernel<<<256, HID, 0, stream>>>(bufA, NN, psum, psumsq);
    finalize_stats<<<HID, 64, 0, stream>>>(psum, psumsq, bns_g + i * HID, bns_b + i * HID,
                                           1.0f / NN, scale, shift);
    wfold_kernel<<<HID, 256, 0, stream>>>(Wg + (size_t)i * HID * HID, scale, shift,
                                          nullptr, Wgt, bias2, HID);
    // xp = bf16(BN(h)@Wg[i]) with fused, direct-store attention logits
    gemm_bf16_kernel<<<dim3((NN + 127) / 128, 2), 256, 0, stream>>>(
        bufA, Wgt, bias2, xp, NN, HID, 0, als, ald,
        att_src + i * HID, att_dst + i * HID);
    gat_agg_kernel<<<(NN + 3) / 4, 256, 0, stream>>>(rp, col, als, ald, xp,
                                                     gat_b + i * HID, bufA);
  }

  // ---- pool + fused tail
  hipMemsetAsync(g0, 0, (size_t)NG * HID * 4, stream);
  pool_kernel<<<256, HID, 0, stream>>>(bufA, batch, g0);
  fc_bn_kernel<<<NG, HID, 0, stream>>>(g0, bn_fc_g, bn_fc_b, W_fc, b_fc, g1);
  cls_bn_kernel<<<NG, HID, 0, stream>>>(g1, bn_h_g, bn_h_b, W_cls, b_cls, (float*)d_out);
}